// Round 1
// baseline (3276.928 us; speedup 1.0000x reference)
//
#include <hip/hip_runtime.h>

#define B_ 128
#define T_ 512
#define D_ 512
#define H_ 64
#define N3 192   // 3*H

__device__ __forceinline__ float sigm_f(float x) {
  return 1.0f / (1.0f + __expf(-x));
}
__device__ __forceinline__ float tanh_f(float x) {
  float e = __expf(-2.0f * fabsf(x));
  float t = (1.0f - e) / (1.0f + e);
  return copysignf(t, x);
}
__device__ __forceinline__ float hsum4(float4 v) { return v.x + v.y + v.z + v.w; }

// ---------------- weight prepack for the scan ----------------
// packw[(m*16 + c)*N3 + j] = float4{ W_m[j][4c..4c+3] }   (m: 0=W0hh,1=W1ih,2=W1hh,3=W2ih,4=W2hh)
// Wave reading chunk (m,c): lanes j..j+63 -> 1KB contiguous (perfect coalescing).
__global__ void prepack_kernel(const float* __restrict__ w0hh,
                               const float* __restrict__ w1ih,
                               const float* __restrict__ w1hh,
                               const float* __restrict__ w2ih,
                               const float* __restrict__ w2hh,
                               float4* __restrict__ packw) {
  int idx = blockIdx.x * blockDim.x + threadIdx.x;
  if (idx >= 5 * 16 * N3) return;
  int m = idx / (16 * N3);
  int rem = idx % (16 * N3);
  int c = rem / N3;
  int j = rem % N3;
  const float* src = (m == 0) ? w0hh : (m == 1) ? w1ih : (m == 2) ? w1hh
                    : (m == 3) ? w2ih : w2hh;
  packw[idx] = *(const float4*)&src[j * H_ + 4 * c];
}

// ---------------- pass 1: gi0 = x @ W0ih^T + b0ih, plus act[t] flags ----------------
// grid: (B * Tc/64, 3), block 256.  Tile 64x64, BK=32, LDS padded [64][33].
__global__ __launch_bounds__(256) void gemm_kernel(
    const float* __restrict__ x,     // [B,T,D]
    const float* __restrict__ w0ih,  // [N3,D]
    const float* __restrict__ b0ih,  // [N3]
    float* __restrict__ gi0,         // [B,Tc,N3]
    int* __restrict__ act,           // [T]
    int t0, int Tc) {
  __shared__ float Xs[64][33];
  __shared__ float Ws[64][33];
  __shared__ unsigned char sflag[64];

  int tid = threadIdx.x;
  int tpc = Tc >> 6;
  int b  = blockIdx.x / tpc;
  int tt = blockIdx.x % tpc;
  int c0 = blockIdx.y * 64;

  int tx = tid & 15, ty = tid >> 4;
  int r1  = tid >> 3;   // [0,32)
  int kc1 = tid & 7;    // [0,8)

  const float* xbase = x + ((size_t)b * T_ + t0 + tt * 64) * D_;
  const float* wbase = w0ih + (size_t)c0 * D_;

  float acc[4][4];
#pragma unroll
  for (int i = 0; i < 4; i++)
#pragma unroll
    for (int q = 0; q < 4; q++) acc[i][q] = 0.0f;

  bool f1 = false, f2 = false;

  for (int kt = 0; kt < D_ / 32; ++kt) {
    float4 va = *(const float4*)&xbase[(size_t)r1 * D_ + kt * 32 + kc1 * 4];
    float4 vb = *(const float4*)&xbase[(size_t)(r1 + 32) * D_ + kt * 32 + kc1 * 4];
    float4 wa = *(const float4*)&wbase[(size_t)r1 * D_ + kt * 32 + kc1 * 4];
    float4 wb = *(const float4*)&wbase[(size_t)(r1 + 32) * D_ + kt * 32 + kc1 * 4];
    f1 |= (va.x != 0.0f) | (va.y != 0.0f) | (va.z != 0.0f) | (va.w != 0.0f);
    f2 |= (vb.x != 0.0f) | (vb.y != 0.0f) | (vb.z != 0.0f) | (vb.w != 0.0f);
    __syncthreads();
    Xs[r1][kc1 * 4 + 0] = va.x; Xs[r1][kc1 * 4 + 1] = va.y;
    Xs[r1][kc1 * 4 + 2] = va.z; Xs[r1][kc1 * 4 + 3] = va.w;
    Xs[r1 + 32][kc1 * 4 + 0] = vb.x; Xs[r1 + 32][kc1 * 4 + 1] = vb.y;
    Xs[r1 + 32][kc1 * 4 + 2] = vb.z; Xs[r1 + 32][kc1 * 4 + 3] = vb.w;
    Ws[r1][kc1 * 4 + 0] = wa.x; Ws[r1][kc1 * 4 + 1] = wa.y;
    Ws[r1][kc1 * 4 + 2] = wa.z; Ws[r1][kc1 * 4 + 3] = wa.w;
    Ws[r1 + 32][kc1 * 4 + 0] = wb.x; Ws[r1 + 32][kc1 * 4 + 1] = wb.y;
    Ws[r1 + 32][kc1 * 4 + 2] = wb.z; Ws[r1 + 32][kc1 * 4 + 3] = wb.w;
    __syncthreads();
#pragma unroll
    for (int k = 0; k < 32; ++k) {
      float a_[4], b_[4];
#pragma unroll
      for (int i = 0; i < 4; i++) a_[i] = Xs[ty * 4 + i][k];
#pragma unroll
      for (int q = 0; q < 4; q++) b_[q] = Ws[tx * 4 + q][k];
#pragma unroll
      for (int i = 0; i < 4; i++)
#pragma unroll
        for (int q = 0; q < 4; q++) acc[i][q] = fmaf(a_[i], b_[q], acc[i][q]);
    }
  }

  float4 bias = *(const float4*)&b0ih[c0 + tx * 4];
#pragma unroll
  for (int i = 0; i < 4; i++) {
    int tloc = tt * 64 + ty * 4 + i;
    float4 o;
    o.x = acc[i][0] + bias.x;
    o.y = acc[i][1] + bias.y;
    o.z = acc[i][2] + bias.z;
    o.w = acc[i][3] + bias.w;
    *(float4*)&gi0[((size_t)b * Tc + tloc) * N3 + c0 + tx * 4] = o;
  }

  if (tid < 64) sflag[tid] = 0;
  __syncthreads();
  if (f1) sflag[r1] = 1;
  if (f2) sflag[r1 + 32] = 1;
  __syncthreads();
  if (tid < 64 && sflag[tid]) act[t0 + tt * 64 + tid] = 1;
}

// ---------------- pass 2: sequential scan, one WG per batch row ----------------
__global__ __launch_bounds__(192) void scan_kernel(
    const float* __restrict__ gi0,     // [B,Tc,N3]
    const float4* __restrict__ packw,  // [5*16*N3]
    const float* __restrict__ b0hh, const float* __restrict__ b1ih,
    const float* __restrict__ b1hh, const float* __restrict__ b2ih,
    const float* __restrict__ b2hh,
    const int* __restrict__ act,       // [T]
    float* __restrict__ hstate,        // [3,B,H]
    float* __restrict__ out,           // [B,T,H]
    int t0, int Tc) {
  int b = blockIdx.x;
  int j = threadIdx.x;
  __shared__ __align__(16) float sh[3][H_];
  __shared__ float s_gi[N3], s_gh[N3];
  __shared__ int s_act[T_];

  if (j < H_) {
    if (t0 == 0) {
      sh[0][j] = 0.0f; sh[1][j] = 0.0f; sh[2][j] = 0.0f;
    } else {
      sh[0][j] = hstate[0 * B_ * H_ + b * H_ + j];
      sh[1][j] = hstate[1 * B_ * H_ + b * H_ + j];
      sh[2][j] = hstate[2 * B_ * H_ + b * H_ + j];
    }
  }
  for (int i = j; i < Tc; i += 192) s_act[i] = act[t0 + i];
  float bh0 = b0hh[j], bi1 = b1ih[j], bh1 = b1hh[j], bi2 = b2ih[j], bh2 = b2hh[j];
  __syncthreads();

  const float* girow = gi0 + (size_t)b * Tc * N3 + j;
  float gi_next = girow[0];

  for (int t = 0; t < Tc; ++t) {
    float gij = gi_next;
    if (t + 1 < Tc) gi_next = girow[(size_t)(t + 1) * N3];
    if (s_act[t]) {
      const float4* h0v = (const float4*)sh[0];
      const float4* h1v = (const float4*)sh[1];
      const float4* h2v = (const float4*)sh[2];
      // layer 0: gh = W0hh @ h0 + b0hh   (gi precomputed)
      float4 a0 = {0, 0, 0, 0};
#pragma unroll
      for (int c = 0; c < 16; c++) {
        float4 w = packw[c * N3 + j];
        float4 h = h0v[c];
        a0.x = fmaf(w.x, h.x, a0.x); a0.y = fmaf(w.y, h.y, a0.y);
        a0.z = fmaf(w.z, h.z, a0.z); a0.w = fmaf(w.w, h.w, a0.w);
      }
      s_gi[j] = gij;
      s_gh[j] = bh0 + hsum4(a0);
      __syncthreads();
      if (j < H_) {
        float r = sigm_f(s_gi[j] + s_gh[j]);
        float z = sigm_f(s_gi[j + H_] + s_gh[j + H_]);
        float n = tanh_f(s_gi[j + 2 * H_] + r * s_gh[j + 2 * H_]);
        sh[0][j] = (1.0f - z) * n + z * sh[0][j];
      }
      __syncthreads();
      // layer 1: gi = W1ih @ h0new + b1ih ; gh = W1hh @ h1 + b1hh
      float4 a1 = {0, 0, 0, 0}, a2 = {0, 0, 0, 0};
#pragma unroll
      for (int c = 0; c < 16; c++) {
        float4 w1 = packw[(16 + c) * N3 + j];
        float4 w2 = packw[(32 + c) * N3 + j];
        float4 hA = h0v[c];
        float4 hB = h1v[c];
        a1.x = fmaf(w1.x, hA.x, a1.x); a1.y = fmaf(w1.y, hA.y, a1.y);
        a1.z = fmaf(w1.z, hA.z, a1.z); a1.w = fmaf(w1.w, hA.w, a1.w);
        a2.x = fmaf(w2.x, hB.x, a2.x); a2.y = fmaf(w2.y, hB.y, a2.y);
        a2.z = fmaf(w2.z, hB.z, a2.z); a2.w = fmaf(w2.w, hB.w, a2.w);
      }
      s_gi[j] = bi1 + hsum4(a1);
      s_gh[j] = bh1 + hsum4(a2);
      __syncthreads();
      if (j < H_) {
        float r = sigm_f(s_gi[j] + s_gh[j]);
        float z = sigm_f(s_gi[j + H_] + s_gh[j + H_]);
        float n = tanh_f(s_gi[j + 2 * H_] + r * s_gh[j + 2 * H_]);
        sh[1][j] = (1.0f - z) * n + z * sh[1][j];
      }
      __syncthreads();
      // layer 2: gi = W2ih @ h1new + b2ih ; gh = W2hh @ h2 + b2hh
      float4 a3 = {0, 0, 0, 0}, a4 = {0, 0, 0, 0};
#pragma unroll
      for (int c = 0; c < 16; c++) {
        float4 w1 = packw[(48 + c) * N3 + j];
        float4 w2 = packw[(64 + c) * N3 + j];
        float4 hA = h1v[c];
        float4 hB = h2v[c];
        a3.x = fmaf(w1.x, hA.x, a3.x); a3.y = fmaf(w1.y, hA.y, a3.y);
        a3.z = fmaf(w1.z, hA.z, a3.z); a3.w = fmaf(w1.w, hA.w, a3.w);
        a4.x = fmaf(w2.x, hB.x, a4.x); a4.y = fmaf(w2.y, hB.y, a4.y);
        a4.z = fmaf(w2.z, hB.z, a4.z); a4.w = fmaf(w2.w, hB.w, a4.w);
      }
      s_gi[j] = bi2 + hsum4(a3);
      s_gh[j] = bh2 + hsum4(a4);
      __syncthreads();
      if (j < H_) {
        float r = sigm_f(s_gi[j] + s_gh[j]);
        float z = sigm_f(s_gi[j + H_] + s_gh[j + H_]);
        float n = tanh_f(s_gi[j + 2 * H_] + r * s_gh[j + 2 * H_]);
        float hn2 = (1.0f - z) * n + z * sh[2][j];
        sh[2][j] = hn2;
        out[((size_t)b * T_ + t0 + t) * H_ + j] = hn2;
      }
      __syncthreads();
    } else {
      if (j < H_) out[((size_t)b * T_ + t0 + t) * H_ + j] = 0.0f;
    }
  }
  if (j < H_) {
    hstate[0 * B_ * H_ + b * H_ + j] = sh[0][j];
    hstate[1 * B_ * H_ + b * H_ + j] = sh[1][j];
    hstate[2 * B_ * H_ + b * H_ + j] = sh[2][j];
  }
}

extern "C" void kernel_launch(void* const* d_in, const int* in_sizes, int n_in,
                              void* d_out, int out_size, void* d_ws, size_t ws_size,
                              hipStream_t stream) {
  const float* x    = (const float*)d_in[0];
  const float* w0ih = (const float*)d_in[1];
  const float* w0hh = (const float*)d_in[2];
  const float* b0ih = (const float*)d_in[3];
  const float* b0hh = (const float*)d_in[4];
  const float* w1ih = (const float*)d_in[5];
  const float* w1hh = (const float*)d_in[6];
  const float* b1ih = (const float*)d_in[7];
  const float* b1hh = (const float*)d_in[8];
  const float* w2ih = (const float*)d_in[9];
  const float* w2hh = (const float*)d_in[10];
  const float* b2ih = (const float*)d_in[11];
  const float* b2hh = (const float*)d_in[12];
  float* out = (float*)d_out;

  char* p = (char*)d_ws;
  float4* packw = (float4*)p; p += (size_t)5 * 16 * N3 * 16;  // 245760 B
  int* act      = (int*)p;    p += 4096;
  float* hstate = (float*)p;  p += (size_t)3 * B_ * H_ * 4;   // 98304 B
  size_t fixed = (size_t)(p - (char*)d_ws);

  int Tc = T_;
  while (Tc > 64 && fixed + (size_t)B_ * Tc * N3 * 4 > ws_size) Tc >>= 1;
  float* gi0 = (float*)p;

  hipMemsetAsync(act, 0, T_ * sizeof(int), stream);
  prepack_kernel<<<(5 * 16 * N3 + 255) / 256, 256, 0, stream>>>(
      w0hh, w1ih, w1hh, w2ih, w2hh, packw);
  for (int t0 = 0; t0 < T_; t0 += Tc) {
    gemm_kernel<<<dim3(B_ * (Tc / 64), 3), 256, 0, stream>>>(
        x, w0ih, b0ih, gi0, act, t0, Tc);
    scan_kernel<<<B_, 192, 0, stream>>>(
        gi0, packw, b0hh, b1ih, b1hh, b2ih, b2hh, act, hstate, out, t0, Tc);
  }
}

// Round 2
// 1259.452 us; speedup vs baseline: 2.6019x; 2.6019x over previous
//
#include <hip/hip_runtime.h>

#define B_ 128
#define T_ 512
#define D_ 512
#define H_ 64
#define N3 192   // 3*H

__device__ __forceinline__ float sigm_f(float x) {
  return 1.0f / (1.0f + __expf(-x));
}
__device__ __forceinline__ float tanh_f(float x) {
  float e = __expf(-2.0f * fabsf(x));
  float t = (1.0f - e) / (1.0f + e);
  return copysignf(t, x);
}
// sum across the 8 lanes of a g-group (lanes jj*8+g, g=0..7; xor 1,2,4 stay in-wave)
__device__ __forceinline__ float red8(float v) {
  v += __shfl_xor(v, 1);
  v += __shfl_xor(v, 2);
  v += __shfl_xor(v, 4);
  return v;
}
__device__ __forceinline__ float dot8(float4 wa, float4 wb, float4 ha, float4 hb) {
  float s = wa.x * ha.x;
  s = fmaf(wa.y, ha.y, s);
  s = fmaf(wa.z, ha.z, s);
  s = fmaf(wa.w, ha.w, s);
  s = fmaf(wb.x, hb.x, s);
  s = fmaf(wb.y, hb.y, s);
  s = fmaf(wb.z, hb.z, s);
  s = fmaf(wb.w, hb.w, s);
  return s;
}

// ---------------- pass 1: gi0 = x @ W0ih^T + b0ih, plus act[t] flags ----------------
// grid: (B * Tc/64, 3), block 256.  Tile 64x64, BK=32, LDS padded [64][33].
__global__ __launch_bounds__(256) void gemm_kernel(
    const float* __restrict__ x,     // [B,T,D]
    const float* __restrict__ w0ih,  // [N3,D]
    const float* __restrict__ b0ih,  // [N3]
    float* __restrict__ gi0,         // [B,Tc,N3]
    int* __restrict__ act,           // [T]
    int t0, int Tc) {
  __shared__ float Xs[64][33];
  __shared__ float Ws[64][33];
  __shared__ unsigned char sflag[64];

  int tid = threadIdx.x;
  int tpc = Tc >> 6;
  int b  = blockIdx.x / tpc;
  int tt = blockIdx.x % tpc;
  int c0 = blockIdx.y * 64;

  int tx = tid & 15, ty = tid >> 4;
  int r1  = tid >> 3;   // [0,32)
  int kc1 = tid & 7;    // [0,8)

  const float* xbase = x + ((size_t)b * T_ + t0 + tt * 64) * D_;
  const float* wbase = w0ih + (size_t)c0 * D_;

  float acc[4][4];
#pragma unroll
  for (int i = 0; i < 4; i++)
#pragma unroll
    for (int q = 0; q < 4; q++) acc[i][q] = 0.0f;

  bool f1 = false, f2 = false;

  for (int kt = 0; kt < D_ / 32; ++kt) {
    float4 va = *(const float4*)&xbase[(size_t)r1 * D_ + kt * 32 + kc1 * 4];
    float4 vb = *(const float4*)&xbase[(size_t)(r1 + 32) * D_ + kt * 32 + kc1 * 4];
    float4 wa = *(const float4*)&wbase[(size_t)r1 * D_ + kt * 32 + kc1 * 4];
    float4 wb = *(const float4*)&wbase[(size_t)(r1 + 32) * D_ + kt * 32 + kc1 * 4];
    f1 |= (va.x != 0.0f) | (va.y != 0.0f) | (va.z != 0.0f) | (va.w != 0.0f);
    f2 |= (vb.x != 0.0f) | (vb.y != 0.0f) | (vb.z != 0.0f) | (vb.w != 0.0f);
    __syncthreads();
    Xs[r1][kc1 * 4 + 0] = va.x; Xs[r1][kc1 * 4 + 1] = va.y;
    Xs[r1][kc1 * 4 + 2] = va.z; Xs[r1][kc1 * 4 + 3] = va.w;
    Xs[r1 + 32][kc1 * 4 + 0] = vb.x; Xs[r1 + 32][kc1 * 4 + 1] = vb.y;
    Xs[r1 + 32][kc1 * 4 + 2] = vb.z; Xs[r1 + 32][kc1 * 4 + 3] = vb.w;
    Ws[r1][kc1 * 4 + 0] = wa.x; Ws[r1][kc1 * 4 + 1] = wa.y;
    Ws[r1][kc1 * 4 + 2] = wa.z; Ws[r1][kc1 * 4 + 3] = wa.w;
    Ws[r1 + 32][kc1 * 4 + 0] = wb.x; Ws[r1 + 32][kc1 * 4 + 1] = wb.y;
    Ws[r1 + 32][kc1 * 4 + 2] = wb.z; Ws[r1 + 32][kc1 * 4 + 3] = wb.w;
    __syncthreads();
#pragma unroll
    for (int k = 0; k < 32; ++k) {
      float a_[4], b_[4];
#pragma unroll
      for (int i = 0; i < 4; i++) a_[i] = Xs[ty * 4 + i][k];
#pragma unroll
      for (int q = 0; q < 4; q++) b_[q] = Ws[tx * 4 + q][k];
#pragma unroll
      for (int i = 0; i < 4; i++)
#pragma unroll
        for (int q = 0; q < 4; q++) acc[i][q] = fmaf(a_[i], b_[q], acc[i][q]);
    }
  }

  float4 bias = *(const float4*)&b0ih[c0 + tx * 4];
#pragma unroll
  for (int i = 0; i < 4; i++) {
    int tloc = tt * 64 + ty * 4 + i;
    float4 o;
    o.x = acc[i][0] + bias.x;
    o.y = acc[i][1] + bias.y;
    o.z = acc[i][2] + bias.z;
    o.w = acc[i][3] + bias.w;
    *(float4*)&gi0[((size_t)b * Tc + tloc) * N3 + c0 + tx * 4] = o;
  }

  if (tid < 64) sflag[tid] = 0;
  __syncthreads();
  if (f1) sflag[r1] = 1;
  if (f2) sflag[r1 + 32] = 1;
  __syncthreads();
  if (tid < 64 && sflag[tid]) act[t0 + tt * 64 + tid] = 1;
}

// ---------------- pass 2: sequential scan, one WG (512 thr) per batch row ----------------
// Thread (jj = tid>>3, g = tid&7): holds weight segments [8g,8g+8) of rows
// {jj, jj+64, jj+128} of all 5 [192][64] matrices in VGPRs (120 VGPRs).
// Per phase: 8-FMA partial dots -> shfl_xor reduce over g -> local (redundant)
// gate math -> g==0 writes new h to LDS. 2 barriers per timestep.
__global__ __launch_bounds__(512, 2) void scan_kernel(
    const float* __restrict__ gi0,   // [B,Tc,N3]
    const float* __restrict__ w0hh, const float* __restrict__ w1ih,
    const float* __restrict__ w1hh, const float* __restrict__ w2ih,
    const float* __restrict__ w2hh,
    const float* __restrict__ b0hh, const float* __restrict__ b1ih,
    const float* __restrict__ b1hh, const float* __restrict__ b2ih,
    const float* __restrict__ b2hh,
    const int* __restrict__ act,     // [T]
    float* __restrict__ hstate,      // [3,B,H]
    float* __restrict__ out,         // [B,T,H]
    int t0, int Tc) {
  const int b   = blockIdx.x;
  const int tid = threadIdx.x;
  const int jj  = tid >> 3;   // [0,64) hidden unit
  const int g   = tid & 7;    // [0,8) segment

  __shared__ __align__(16) float s_h[3][2][H_];   // [layer][parity][unit]
  __shared__ __align__(16) float s_out[32][H_];
  __shared__ int s_act[T_];

  // ---- load weights into registers (one-time) ----
  float4 wv[5][3][2];
  const float* wp[5] = {w0hh, w1ih, w1hh, w2ih, w2hh};
#pragma unroll
  for (int m = 0; m < 5; m++)
#pragma unroll
    for (int r = 0; r < 3; r++) {
      const float* src = wp[m] + (size_t)(jj + 64 * r) * H_ + 8 * g;
      wv[m][r][0] = *(const float4*)src;
      wv[m][r][1] = *(const float4*)(src + 4);
    }
  float bs[5][3];
  const float* bp[5] = {b0hh, b1ih, b1hh, b2ih, b2hh};
#pragma unroll
  for (int m = 0; m < 5; m++)
#pragma unroll
    for (int r = 0; r < 3; r++) bs[m][r] = bp[m][jj + 64 * r];

  // ---- h state: register copy (per jj, replicated over g) + LDS copy ----
  float h0, h1, h2;
  if (t0 == 0) {
    h0 = 0.0f; h1 = 0.0f; h2 = 0.0f;
  } else {
    h0 = hstate[0 * B_ * H_ + b * H_ + jj];
    h1 = hstate[1 * B_ * H_ + b * H_ + jj];
    h2 = hstate[2 * B_ * H_ + b * H_ + jj];
  }
  if (tid < H_) {
    s_h[0][0][tid] = (t0 == 0) ? 0.0f : hstate[0 * B_ * H_ + b * H_ + tid];
    s_h[1][0][tid] = (t0 == 0) ? 0.0f : hstate[1 * B_ * H_ + b * H_ + tid];
    s_h[2][0][tid] = (t0 == 0) ? 0.0f : hstate[2 * B_ * H_ + b * H_ + tid];
  }
  for (int i = tid; i < Tc; i += 512) s_act[i] = act[t0 + i];
  __syncthreads();

  const float* gibase = gi0 + (size_t)b * Tc * N3;
  int cur = 0;
  float giR = gibase[jj], giZ = gibase[jj + 64], giN = gibase[jj + 128];

  for (int t = 0; t < Tc; ++t) {
    // prefetch next step's gi
    int tn = (t + 1 < Tc) ? t + 1 : t;
    const float* gin = gibase + (size_t)tn * N3;
    float nR = gin[jj], nZ = gin[jj + 64], nN = gin[jj + 128];

    if (s_act[t]) {
      // ---- layer 0: gh = W0hh @ h0 ----
      const float4* hp = (const float4*)s_h[0][cur];
      float4 ha = hp[2 * g], hb = hp[2 * g + 1];
      float dR = red8(dot8(wv[0][0][0], wv[0][0][1], ha, hb)) + bs[0][0];
      float dZ = red8(dot8(wv[0][1][0], wv[0][1][1], ha, hb)) + bs[0][1];
      float dN = red8(dot8(wv[0][2][0], wv[0][2][1], ha, hb)) + bs[0][2];
      {
        float r = sigm_f(giR + dR);
        float z = sigm_f(giZ + dZ);
        float n = tanh_f(giN + r * dN);
        h0 = (1.0f - z) * n + z * h0;
      }
      if (g == 0) s_h[0][cur ^ 1][jj] = h0;
      __syncthreads();

      // ---- layer 1: gi = W1ih @ h0new ; gh = W1hh @ h1 ----
      const float4* hp0 = (const float4*)s_h[0][cur ^ 1];
      const float4* hp1 = (const float4*)s_h[1][cur];
      float4 a0 = hp0[2 * g], a1 = hp0[2 * g + 1];
      float4 c0 = hp1[2 * g], c1 = hp1[2 * g + 1];
      float iR = red8(dot8(wv[1][0][0], wv[1][0][1], a0, a1)) + bs[1][0];
      float iZ = red8(dot8(wv[1][1][0], wv[1][1][1], a0, a1)) + bs[1][1];
      float iN = red8(dot8(wv[1][2][0], wv[1][2][1], a0, a1)) + bs[1][2];
      float hR = red8(dot8(wv[2][0][0], wv[2][0][1], c0, c1)) + bs[2][0];
      float hZ = red8(dot8(wv[2][1][0], wv[2][1][1], c0, c1)) + bs[2][1];
      float hN = red8(dot8(wv[2][2][0], wv[2][2][1], c0, c1)) + bs[2][2];
      {
        float r = sigm_f(iR + hR);
        float z = sigm_f(iZ + hZ);
        float n = tanh_f(iN + r * hN);
        h1 = (1.0f - z) * n + z * h1;
      }
      if (g == 0) s_h[1][cur ^ 1][jj] = h1;
      __syncthreads();

      // ---- layer 2: gi = W2ih @ h1new ; gh = W2hh @ h2 ----
      const float4* hq1 = (const float4*)s_h[1][cur ^ 1];
      const float4* hq2 = (const float4*)s_h[2][cur];
      float4 e0 = hq1[2 * g], e1 = hq1[2 * g + 1];
      float4 f0 = hq2[2 * g], f1 = hq2[2 * g + 1];
      float jR = red8(dot8(wv[3][0][0], wv[3][0][1], e0, e1)) + bs[3][0];
      float jZ = red8(dot8(wv[3][1][0], wv[3][1][1], e0, e1)) + bs[3][1];
      float jN = red8(dot8(wv[3][2][0], wv[3][2][1], e0, e1)) + bs[3][2];
      float kR = red8(dot8(wv[4][0][0], wv[4][0][1], f0, f1)) + bs[4][0];
      float kZ = red8(dot8(wv[4][1][0], wv[4][1][1], f0, f1)) + bs[4][1];
      float kN = red8(dot8(wv[4][2][0], wv[4][2][1], f0, f1)) + bs[4][2];
      {
        float r = sigm_f(jR + kR);
        float z = sigm_f(jZ + kZ);
        float n = tanh_f(jN + r * kN);
        h2 = (1.0f - z) * n + z * h2;
      }
      if (g == 0) {
        s_h[2][cur ^ 1][jj] = h2;
        s_out[t & 31][jj] = h2;
      }
      // no barrier needed here: next step's two barriers order the L2 buffers
      cur ^= 1;
    } else {
      if (g == 0) s_out[t & 31][jj] = 0.0f;
    }

    giR = nR; giZ = nZ; giN = nN;

    if ((t & 31) == 31) {            // coalesced output flush (Tc % 32 == 0)
      __syncthreads();
      int row = tid >> 4, c4 = (tid & 15) * 4;
      *(float4*)&out[((size_t)b * T_ + t0 + (t - 31) + row) * H_ + c4] =
          *(const float4*)&s_out[row][c4];
      __syncthreads();
    }
  }

  if (g == 0) {
    hstate[0 * B_ * H_ + b * H_ + jj] = h0;
    hstate[1 * B_ * H_ + b * H_ + jj] = h1;
    hstate[2 * B_ * H_ + b * H_ + jj] = h2;
  }
}

extern "C" void kernel_launch(void* const* d_in, const int* in_sizes, int n_in,
                              void* d_out, int out_size, void* d_ws, size_t ws_size,
                              hipStream_t stream) {
  const float* x    = (const float*)d_in[0];
  const float* w0ih = (const float*)d_in[1];
  const float* w0hh = (const float*)d_in[2];
  const float* b0ih = (const float*)d_in[3];
  const float* b0hh = (const float*)d_in[4];
  const float* w1ih = (const float*)d_in[5];
  const float* w1hh = (const float*)d_in[6];
  const float* b1ih = (const float*)d_in[7];
  const float* b1hh = (const float*)d_in[8];
  const float* w2ih = (const float*)d_in[9];
  const float* w2hh = (const float*)d_in[10];
  const float* b2ih = (const float*)d_in[11];
  const float* b2hh = (const float*)d_in[12];
  float* out = (float*)d_out;

  char* p = (char*)d_ws;
  int* act      = (int*)p;    p += 4096;
  float* hstate = (float*)p;  p += (size_t)3 * B_ * H_ * 4;   // 98304 B
  size_t fixed = (size_t)(p - (char*)d_ws);

  int Tc = T_;
  while (Tc > 64 && fixed + (size_t)B_ * Tc * N3 * 4 > ws_size) Tc >>= 1;
  float* gi0 = (float*)p;

  hipMemsetAsync(act, 0, T_ * sizeof(int), stream);
  for (int t0 = 0; t0 < T_; t0 += Tc) {
    gemm_kernel<<<dim3(B_ * (Tc / 64), 3), 256, 0, stream>>>(
        x, w0ih, b0ih, gi0, act, t0, Tc);
    scan_kernel<<<B_, 512, 0, stream>>>(
        gi0, w0hh, w1ih, w1hh, w2ih, w2hh,
        b0hh, b1ih, b1hh, b2ih, b2hh, act, hstate, out, t0, Tc);
  }
}

// Round 4
// 1017.080 us; speedup vs baseline: 3.2219x; 1.2383x over previous
//
#include <hip/hip_runtime.h>

#define B_ 128
#define T_ 512
#define D_ 512
#define H_ 64
#define N3 192   // 3*H

__device__ __forceinline__ float sigm_f(float x) {
  return 1.0f / (1.0f + __expf(-x));
}
__device__ __forceinline__ float tanh_f(float x) {
  float e = __expf(-2.0f * fabsf(x));
  float t = (1.0f - e) / (1.0f + e);
  return copysignf(t, x);
}

// 8-lane sum over lanes jj*8+g (g=0..7) entirely on the VALU via DPP:
// xor1 = quad_perm[1,0,3,2]=0xB1, xor2 = quad_perm[2,3,0,1]=0x4E,
// xor4 = row_half_mirror = 0x141.
template <int CTRL>
__device__ __forceinline__ float dpp_add(float v) {
  int t = __builtin_amdgcn_update_dpp(0, __float_as_int(v), CTRL, 0xF, 0xF, true);
  return v + __int_as_float(t);
}
__device__ __forceinline__ float red8(float v) {
  v = dpp_add<0xB1>(v);
  v = dpp_add<0x4E>(v);
  v = dpp_add<0x141>(v);
  return v;
}

__device__ __forceinline__ float dot8(float4 wa, float4 wb, float4 ha, float4 hb) {
  // two independent chains for ILP
  float s0 = wa.x * ha.x;
  float s1 = wa.y * ha.y;
  s0 = fmaf(wa.z, ha.z, s0);
  s1 = fmaf(wa.w, ha.w, s1);
  s0 = fmaf(wb.x, hb.x, s0);
  s1 = fmaf(wb.y, hb.y, s1);
  s0 = fmaf(wb.z, hb.z, s0);
  s1 = fmaf(wb.w, hb.w, s1);
  return s0 + s1;
}

#define KEEP(x) asm volatile("" : "+v"(x))
#define KEEP4(v) do { KEEP((v).x); KEEP((v).y); KEEP((v).z); KEEP((v).w); } while (0)

// ---------------- pass 1: gi0 = x @ W0ih^T + b0ih, plus act[t] flags ----------------
__global__ __launch_bounds__(256) void gemm_kernel(
    const float* __restrict__ x,     // [B,T,D]
    const float* __restrict__ w0ih,  // [N3,D]
    const float* __restrict__ b0ih,  // [N3]
    float* __restrict__ gi0,         // [B,Tc,N3]
    int* __restrict__ act,           // [T]
    int t0, int Tc) {
  __shared__ float Xs[64][33];
  __shared__ float Ws[64][33];
  __shared__ unsigned char sflag[64];

  int tid = threadIdx.x;
  int tpc = Tc >> 6;
  int b  = blockIdx.x / tpc;
  int tt = blockIdx.x % tpc;
  int c0 = blockIdx.y * 64;

  int tx = tid & 15, ty = tid >> 4;
  int r1  = tid >> 3;   // [0,32)
  int kc1 = tid & 7;    // [0,8)

  const float* xbase = x + ((size_t)b * T_ + t0 + tt * 64) * D_;
  const float* wbase = w0ih + (size_t)c0 * D_;

  float acc[4][4];
#pragma unroll
  for (int i = 0; i < 4; i++)
#pragma unroll
    for (int q = 0; q < 4; q++) acc[i][q] = 0.0f;

  bool f1 = false, f2 = false;

  for (int kt = 0; kt < D_ / 32; ++kt) {
    float4 va = *(const float4*)&xbase[(size_t)r1 * D_ + kt * 32 + kc1 * 4];
    float4 vb = *(const float4*)&xbase[(size_t)(r1 + 32) * D_ + kt * 32 + kc1 * 4];
    float4 wa = *(const float4*)&wbase[(size_t)r1 * D_ + kt * 32 + kc1 * 4];
    float4 wb = *(const float4*)&wbase[(size_t)(r1 + 32) * D_ + kt * 32 + kc1 * 4];
    f1 |= (va.x != 0.0f) | (va.y != 0.0f) | (va.z != 0.0f) | (va.w != 0.0f);
    f2 |= (vb.x != 0.0f) | (vb.y != 0.0f) | (vb.z != 0.0f) | (vb.w != 0.0f);
    __syncthreads();
    Xs[r1][kc1 * 4 + 0] = va.x; Xs[r1][kc1 * 4 + 1] = va.y;
    Xs[r1][kc1 * 4 + 2] = va.z; Xs[r1][kc1 * 4 + 3] = va.w;
    Xs[r1 + 32][kc1 * 4 + 0] = vb.x; Xs[r1 + 32][kc1 * 4 + 1] = vb.y;
    Xs[r1 + 32][kc1 * 4 + 2] = vb.z; Xs[r1 + 32][kc1 * 4 + 3] = vb.w;
    Ws[r1][kc1 * 4 + 0] = wa.x; Ws[r1][kc1 * 4 + 1] = wa.y;
    Ws[r1][kc1 * 4 + 2] = wa.z; Ws[r1][kc1 * 4 + 3] = wa.w;
    Ws[r1 + 32][kc1 * 4 + 0] = wb.x; Ws[r1 + 32][kc1 * 4 + 1] = wb.y;
    Ws[r1 + 32][kc1 * 4 + 2] = wb.z; Ws[r1 + 32][kc1 * 4 + 3] = wb.w;
    __syncthreads();
#pragma unroll
    for (int k = 0; k < 32; ++k) {
      float a_[4], b_[4];
#pragma unroll
      for (int i = 0; i < 4; i++) a_[i] = Xs[ty * 4 + i][k];
#pragma unroll
      for (int q = 0; q < 4; q++) b_[q] = Ws[tx * 4 + q][k];
#pragma unroll
      for (int i = 0; i < 4; i++)
#pragma unroll
        for (int q = 0; q < 4; q++) acc[i][q] = fmaf(a_[i], b_[q], acc[i][q]);
    }
  }

  float4 bias = *(const float4*)&b0ih[c0 + tx * 4];
#pragma unroll
  for (int i = 0; i < 4; i++) {
    int tloc = tt * 64 + ty * 4 + i;
    float4 o;
    o.x = acc[i][0] + bias.x;
    o.y = acc[i][1] + bias.y;
    o.z = acc[i][2] + bias.z;
    o.w = acc[i][3] + bias.w;
    *(float4*)&gi0[((size_t)b * Tc + tloc) * N3 + c0 + tx * 4] = o;
  }

  if (tid < 64) sflag[tid] = 0;
  __syncthreads();
  if (f1) sflag[r1] = 1;
  if (f2) sflag[r1 + 32] = 1;
  __syncthreads();
  if (tid < 64 && sflag[tid]) act[t0 + tt * 64 + tid] = 1;
}

// ---------------- pass 2: sequential scan, one WG (512 thr) per batch row ----------------
// Thread (jj = tid>>3, g = tid&7) permanently holds weight segments [8g,8g+8)
// of rows {jj, jj+64, jj+128} of all 5 [192][64] matrices in VGPRs (120 regs,
// pinned by KEEP asm so the compiler cannot rematerialize from L2).
// Reductions over g are 3 v_add_f32_dpp (no DS traffic). Branchless state
// update; 2 barriers per timestep.
__global__ __launch_bounds__(512, 2) void scan_kernel(
    const float* __restrict__ gi0,   // [B,Tc,N3]
    const float* __restrict__ w0hh, const float* __restrict__ w1ih,
    const float* __restrict__ w1hh, const float* __restrict__ w2ih,
    const float* __restrict__ w2hh,
    const float* __restrict__ b0hh, const float* __restrict__ b1ih,
    const float* __restrict__ b1hh, const float* __restrict__ b2ih,
    const float* __restrict__ b2hh,
    const int* __restrict__ act,     // [T]
    float* __restrict__ hstate,      // [3,B,H]
    float* __restrict__ out,         // [B,T,H]
    int t0, int Tc) {
  const int b   = blockIdx.x;
  const int tid = threadIdx.x;
  const int jj  = tid >> 3;   // [0,64) hidden unit
  const int g   = tid & 7;    // [0,8) segment

  __shared__ __align__(16) float s_h[3][2][H_];   // [layer][parity][unit]
  __shared__ __align__(16) float s_out[32][H_];
  __shared__ int s_act[T_];

  // ---- load weights into registers (one-time), pin with KEEP ----
  float4 wv[5][3][2];
  const float* wp[5] = {w0hh, w1ih, w1hh, w2ih, w2hh};
#pragma unroll
  for (int m = 0; m < 5; m++)
#pragma unroll
    for (int r = 0; r < 3; r++) {
      const float* src = wp[m] + (size_t)(jj + 64 * r) * H_ + 8 * g;
      wv[m][r][0] = *(const float4*)src;
      wv[m][r][1] = *(const float4*)(src + 4);
    }
  float bs[5][3];
  const float* bp[5] = {b0hh, b1ih, b1hh, b2ih, b2hh};
#pragma unroll
  for (int m = 0; m < 5; m++)
#pragma unroll
    for (int r = 0; r < 3; r++) bs[m][r] = bp[m][jj + 64 * r];

#pragma unroll
  for (int m = 0; m < 5; m++)
#pragma unroll
    for (int r = 0; r < 3; r++) {
      KEEP4(wv[m][r][0]);
      KEEP4(wv[m][r][1]);
      KEEP(bs[m][r]);
    }

  // ---- h state: register copy (per jj, replicated over g) + LDS copy ----
  float h0, h1, h2;
  if (t0 == 0) {
    h0 = 0.0f; h1 = 0.0f; h2 = 0.0f;
  } else {
    h0 = hstate[0 * B_ * H_ + b * H_ + jj];
    h1 = hstate[1 * B_ * H_ + b * H_ + jj];
    h2 = hstate[2 * B_ * H_ + b * H_ + jj];
  }
  if (tid < H_) {
    s_h[0][0][tid] = (t0 == 0) ? 0.0f : hstate[0 * B_ * H_ + b * H_ + tid];
    s_h[1][0][tid] = (t0 == 0) ? 0.0f : hstate[1 * B_ * H_ + b * H_ + tid];
    s_h[2][0][tid] = (t0 == 0) ? 0.0f : hstate[2 * B_ * H_ + b * H_ + tid];
  }
  for (int i = tid; i < Tc; i += 512) s_act[i] = act[t0 + i];
  __syncthreads();

  const float* gibase = gi0 + (size_t)b * Tc * N3;
  int cur = 0;
  float giR = gibase[jj], giZ = gibase[jj + 64], giN = gibase[jj + 128];

  for (int t = 0; t < Tc; ++t) {
    // prefetch next step's gi
    int tn = (t + 1 < Tc) ? t + 1 : t;
    const float* gin = gibase + (size_t)tn * N3;
    float nR = gin[jj], nZ = gin[jj + 64], nN = gin[jj + 128];

    const bool a = (s_act[t] != 0);

    // ---- layer 0: gh = W0hh @ h0 ----
    {
      const float4* hp = (const float4*)s_h[0][cur];
      float4 ha = hp[2 * g], hb = hp[2 * g + 1];
      float dR = red8(dot8(wv[0][0][0], wv[0][0][1], ha, hb)) + bs[0][0];
      float dZ = red8(dot8(wv[0][1][0], wv[0][1][1], ha, hb)) + bs[0][1];
      float dN = red8(dot8(wv[0][2][0], wv[0][2][1], ha, hb)) + bs[0][2];
      float r = sigm_f(giR + dR);
      float z = sigm_f(giZ + dZ);
      float n = tanh_f(giN + r * dN);
      float hn = (1.0f - z) * n + z * h0;
      h0 = a ? hn : h0;
    }
    if (g == 0) s_h[0][cur ^ 1][jj] = h0;
    __syncthreads();

    // ---- layer 1: gi = W1ih @ h0new ; gh = W1hh @ h1 ----
    {
      const float4* hp0 = (const float4*)s_h[0][cur ^ 1];
      const float4* hp1 = (const float4*)s_h[1][cur];
      float4 a0 = hp0[2 * g], a1 = hp0[2 * g + 1];
      float4 c0 = hp1[2 * g], c1 = hp1[2 * g + 1];
      float iR = red8(dot8(wv[1][0][0], wv[1][0][1], a0, a1)) + bs[1][0];
      float iZ = red8(dot8(wv[1][1][0], wv[1][1][1], a0, a1)) + bs[1][1];
      float iN = red8(dot8(wv[1][2][0], wv[1][2][1], a0, a1)) + bs[1][2];
      float hR = red8(dot8(wv[2][0][0], wv[2][0][1], c0, c1)) + bs[2][0];
      float hZ = red8(dot8(wv[2][1][0], wv[2][1][1], c0, c1)) + bs[2][1];
      float hN = red8(dot8(wv[2][2][0], wv[2][2][1], c0, c1)) + bs[2][2];
      float r = sigm_f(iR + hR);
      float z = sigm_f(iZ + hZ);
      float n = tanh_f(iN + r * hN);
      float hn = (1.0f - z) * n + z * h1;
      h1 = a ? hn : h1;
    }
    if (g == 0) s_h[1][cur ^ 1][jj] = h1;
    __syncthreads();

    // ---- layer 2: gi = W2ih @ h1new ; gh = W2hh @ h2 ----
    {
      const float4* hq1 = (const float4*)s_h[1][cur ^ 1];
      const float4* hq2 = (const float4*)s_h[2][cur];
      float4 e0 = hq1[2 * g], e1 = hq1[2 * g + 1];
      float4 f0 = hq2[2 * g], f1 = hq2[2 * g + 1];
      float jR = red8(dot8(wv[3][0][0], wv[3][0][1], e0, e1)) + bs[3][0];
      float jZ = red8(dot8(wv[3][1][0], wv[3][1][1], e0, e1)) + bs[3][1];
      float jN = red8(dot8(wv[3][2][0], wv[3][2][1], e0, e1)) + bs[3][2];
      float kR = red8(dot8(wv[4][0][0], wv[4][0][1], f0, f1)) + bs[4][0];
      float kZ = red8(dot8(wv[4][1][0], wv[4][1][1], f0, f1)) + bs[4][1];
      float kN = red8(dot8(wv[4][2][0], wv[4][2][1], f0, f1)) + bs[4][2];
      float r = sigm_f(jR + kR);
      float z = sigm_f(jZ + kZ);
      float n = tanh_f(jN + r * kN);
      float hn = (1.0f - z) * n + z * h2;
      h2 = a ? hn : h2;
    }
    if (g == 0) {
      s_h[2][cur ^ 1][jj] = h2;
      s_out[t & 31][jj] = a ? h2 : 0.0f;
    }
    // no barrier needed: next step's two barriers order these buffers
    cur ^= 1;
    giR = nR; giZ = nZ; giN = nN;

    if ((t & 31) == 31) {            // coalesced output flush (Tc % 32 == 0)
      __syncthreads();
      int row = tid >> 4, c4 = (tid & 15) * 4;
      *(float4*)&out[((size_t)b * T_ + t0 + (t - 31) + row) * H_ + c4] =
          *(const float4*)&s_out[row][c4];
      // next s_out write happens after the next step's barriers -> safe
    }
  }

  if (g == 0) {
    hstate[0 * B_ * H_ + b * H_ + jj] = h0;
    hstate[1 * B_ * H_ + b * H_ + jj] = h1;
    hstate[2 * B_ * H_ + b * H_ + jj] = h2;
  }
}

extern "C" void kernel_launch(void* const* d_in, const int* in_sizes, int n_in,
                              void* d_out, int out_size, void* d_ws, size_t ws_size,
                              hipStream_t stream) {
  const float* x    = (const float*)d_in[0];
  const float* w0ih = (const float*)d_in[1];
  const float* w0hh = (const float*)d_in[2];
  const float* b0ih = (const float*)d_in[3];
  const float* b0hh = (const float*)d_in[4];
  const float* w1ih = (const float*)d_in[5];
  const float* w1hh = (const float*)d_in[6];
  const float* b1ih = (const float*)d_in[7];
  const float* b1hh = (const float*)d_in[8];
  const float* w2ih = (const float*)d_in[9];
  const float* w2hh = (const float*)d_in[10];
  const float* b2ih = (const float*)d_in[11];
  const float* b2hh = (const float*)d_in[12];
  float* out = (float*)d_out;

  char* p = (char*)d_ws;
  int* act      = (int*)p;    p += 4096;
  float* hstate = (float*)p;  p += (size_t)3 * B_ * H_ * 4;
  size_t fixed = (size_t)(p - (char*)d_ws);

  int Tc = T_;
  while (Tc > 64 && fixed + (size_t)B_ * Tc * N3 * 4 > ws_size) Tc >>= 1;
  float* gi0 = (float*)p;

  hipMemsetAsync(act, 0, T_ * sizeof(int), stream);
  for (int t0 = 0; t0 < T_; t0 += Tc) {
    gemm_kernel<<<dim3(B_ * (Tc / 64), 3), 256, 0, stream>>>(
        x, w0ih, b0ih, gi0, act, t0, Tc);
    scan_kernel<<<B_, 512, 0, stream>>>(
        gi0, w0hh, w1ih, w1hh, w2ih, w2hh,
        b0hh, b1ih, b1hh, b2ih, b2hh, act, hstate, out, t0, Tc);
  }
}